// Round 2
// baseline (228.339 us; speedup 1.0000x reference)
//
#include <hip/hip_runtime.h>

constexpr int NB = 8;
constexpr int NN = 8192;
constexpr int NH = 128;
constexpr int NG = 16;
constexpr float EPS = 1e-8f;
constexpr int NBATCH = NB * NN / 4;   // 16384 node-batches of 4

__device__ __forceinline__ float frcp(float x) { return __builtin_amdgcn_rcpf(x); }
__device__ __forceinline__ float fsqrt(float x) { return __builtin_amdgcn_sqrtf(x); }
__device__ __forceinline__ float fsigmoid(float x) { return frcp(1.f + __expf(-x)); }
__device__ __forceinline__ float fsilu(float x) { return x * fsigmoid(x); }
__device__ __forceinline__ float fclamp1(float x) { return fminf(fmaxf(x, -1.f), 1.f); }

// ---------------- K1: vec_geom = vec @ W_geom  (B*N*3, H) @ (H, G) ----------
__global__ __launch_bounds__(256) void k_vecgeom(const float* __restrict__ vec,
                                                 const float* __restrict__ Wg,
                                                 float* __restrict__ vg) {
    __shared__ float Wl[NH * NG];
    for (int t = threadIdx.x; t < NH * NG; t += 256) Wl[t] = Wg[t];
    __syncthreads();

    int idx = blockIdx.x * 256 + threadIdx.x;   // 0 .. B*N*48  (exact grid)
    int node = idx / 48;                        // b*N + n
    int cg = idx % 48;
    int c = cg >> 4, g = cg & 15;
    const float* vrow = vec + (node * 3 + c) * NH;
    float acc = 0.f;
#pragma unroll 8
    for (int h = 0; h < NH; h += 4) {
        float4 v4 = *reinterpret_cast<const float4*>(vrow + h);
        acc = fmaf(v4.x, Wl[(h + 0) * NG + g], acc);
        acc = fmaf(v4.y, Wl[(h + 1) * NG + g], acc);
        acc = fmaf(v4.z, Wl[(h + 2) * NG + g], acc);
        acc = fmaf(v4.w, Wl[(h + 3) * NG + g], acc);
    }
    vg[(node * 3 + c) * NG + g] = acc;
}

// ---------------- K2: u[i] = sum_j normalize(vg[j]-vg[i]) -------------------
__global__ __launch_bounds__(256) void k_u(const float* __restrict__ vg,
                                           float* __restrict__ u) {
    int idx = blockIdx.x * 256 + threadIdx.x;   // 0 .. B*N*16 (exact grid)
    int g = idx & 15;
    int bn = idx >> 4;                          // b*N + n
    int n = bn & (NN - 1);
    int base_i = (bn * 3) * NG + g;
    float vi0 = vg[base_i], vi1 = vg[base_i + NG], vi2 = vg[base_i + 2 * NG];
    float a0 = 0.f, a1 = 0.f, a2 = 0.f;
#pragma unroll
    for (int e = 0; e < 6; ++e) {
        int off = (e < 3) ? (e - 3) : (e - 2);  // -3,-2,-1,1,2,3
        int j = n + off;
        if (j < 0 || j >= NN) continue;
        int base_j = base_i + off * 3 * NG;
        float d0 = vg[base_j] - vi0;
        float d1 = vg[base_j + NG] - vi1;
        float d2 = vg[base_j + 2 * NG] - vi2;
        float nb = fmaxf(fsqrt(d0 * d0 + d1 * d1 + d2 * d2), EPS);
        float r = frcp(nb);
        a0 = fmaf(d0, r, a0); a1 = fmaf(d1, r, a1); a2 = fmaf(d2, r, a2);
    }
    u[base_i] = a0; u[base_i + NG] = a1; u[base_i + 2 * NG] = a2;
}

// ---------------- K3: fused edge features + MLPs + register-resident gate ---
// 256 threads = 4 waves = 4 node-slots per batch; grid-stride over batches.
// Phase A: lane = (edge-group, g).  Phase B: lane = (qk, h-quad); weights for
// the thread's (qk, h-quad) column live in 16 float4 registers for the whole
// kernel (loaded once) — no per-edge weight traffic.
__global__ __launch_bounds__(256) void k_main(
    const float* __restrict__ vg, const float* __restrict__ u,
    const float* __restrict__ xs,
    const float* __restrict__ qw1, const float* __restrict__ qb1,
    const float* __restrict__ qw2, const float* __restrict__ qb2,
    const float* __restrict__ kw1, const float* __restrict__ kb1,
    const float* __restrict__ kw2, const float* __restrict__ kb2,
    const float* __restrict__ Wq, const float* __restrict__ bq,
    const float* __restrict__ Wk, const float* __restrict__ bk,
    float* __restrict__ outq, float* __restrict__ outk) {
    __shared__ float mw[2][2][16];   // [qk][featrow][m]
    __shared__ float mb1s[2][16];
    __shared__ float mw2s[2][16];
    __shared__ float mb2s[2];
    __shared__ __align__(16) float gg[2][4][6][16];  // [qk][nodeSlot][e][g]

    int tid = threadIdx.x;
    if (tid < 16) {
        mw[0][0][tid] = qw1[tid]; mw[0][1][tid] = qw1[16 + tid];
        mb1s[0][tid] = qb1[tid];  mw2s[0][tid] = qw2[tid];
        mw[1][0][tid] = kw1[tid]; mw[1][1][tid] = kw1[16 + tid];
        mb1s[1][tid] = kb1[tid];  mw2s[1][tid] = kw2[tid];
    }
    if (tid == 16) { mb2s[0] = qb2[0]; mb2s[1] = kb2[0]; }

    int lane = tid & 63;
    int wv = tid >> 6;            // node slot 0..3
    int eg = lane >> 4, g = lane & 15;   // phase A mapping
    int qk = lane >> 5, h4 = lane & 31;  // phase B mapping

    // Register-resident gate weights: W{q|k}[:, h4*4 .. h4*4+3]
    const float* Wsel = qk ? Wk : Wq;
    const float* bsel = qk ? bk : bq;
    float* outsel = qk ? outk : outq;
    float4 wreg[16];
#pragma unroll
    for (int gi = 0; gi < 16; ++gi)
        wreg[gi] = *reinterpret_cast<const float4*>(Wsel + gi * NH + h4 * 4);
    float4 b4 = *reinterpret_cast<const float4*>(bsel + h4 * 4);

    __syncthreads();

    for (int batch = blockIdx.x; batch < NBATCH; batch += gridDim.x) {
        int bn = batch * 4 + wv;
        int n = bn & (NN - 1);

        // ---- Phase A: per-edge geometry + tiny MLPs ----
        int base_i = (bn * 3) * NG + g;
        float vi0 = vg[base_i], vi1 = vg[base_i + NG], vi2 = vg[base_i + 2 * NG];
        float ui0 = u[base_i],  ui1 = u[base_i + NG],  ui2 = u[base_i + 2 * NG];
        float rnui = frcp(fmaxf(fsqrt(ui0 * ui0 + ui1 * ui1 + ui2 * ui2), EPS));

#pragma unroll
        for (int r = 0; r < 2; ++r) {
            int e = r * 4 + eg;
            if (e < 6) {
                int off = (e < 3) ? (e - 3) : (e - 2);
                int j = n + off;
                if (j >= 0 && j < NN) {
                    int base_j = base_i + off * 3 * NG;
                    float d0 = vg[base_j] - vi0;
                    float d1 = vg[base_j + NG] - vi1;
                    float d2 = vg[base_j + 2 * NG] - vi2;
                    float rb = frcp(fmaxf(fsqrt(d0 * d0 + d1 * d1 + d2 * d2), EPS));
                    float e0 = d0 * rb, e1 = d1 * rb, e2 = d2 * rb;
                    float uj0 = u[base_j], uj1 = u[base_j + NG], uj2 = u[base_j + 2 * NG];
                    float die = ui0 * e0 + ui1 * e1 + ui2 * e2;
                    float ang = fclamp1(die * rnui);
                    float p0 = ui0 - die * e0, p1 = ui1 - die * e1, p2 = ui2 - die * e2;
                    float dje = uj0 * e0 + uj1 * e1 + uj2 * e2;
                    float q0 = uj0 - dje * e0, q1 = uj1 - dje * e1, q2 = uj2 - dje * e2;
                    float dp = p0 * q0 + p1 * q1 + p2 * q2;
                    float npi = fmaxf(fsqrt(p0 * p0 + p1 * p1 + p2 * p2), EPS);
                    float npj = fmaxf(fsqrt(q0 * q0 + q1 * q1 + q2 * q2), EPS);
                    float dih = fclamp1(dp * frcp(fmaxf(npi * npj, EPS)));

                    float accq = mb2s[0], acck = mb2s[1];
#pragma unroll
                    for (int m = 0; m < 16; ++m) {
                        float hq = fmaf(ang, mw[0][0][m], fmaf(dih, mw[0][1][m], mb1s[0][m]));
                        float hk = fmaf(ang, mw[1][0][m], fmaf(dih, mw[1][1][m], mb1s[1][m]));
                        accq = fmaf(fsilu(hq), mw2s[0][m], accq);
                        acck = fmaf(fsilu(hk), mw2s[1][m], acck);
                    }
                    gg[0][wv][e][g] = accq;
                    gg[1][wv][e][g] = acck;
                }
            }
        }
        __syncthreads();

        // ---- Phase B: dense G->H from registers + sigmoid gate + scatter ----
        float4 acc = make_float4(0.f, 0.f, 0.f, 0.f);
        const float* ggp = &gg[qk][wv][0][0];
#pragma unroll
        for (int e = 0; e < 6; ++e) {
            int off = (e < 3) ? (e - 3) : (e - 2);
            int j = n + off;
            if (j >= 0 && j < NN) {
                float4 s = b4;
#pragma unroll
                for (int t = 0; t < 4; ++t) {
                    float4 g4 = *reinterpret_cast<const float4*>(ggp + e * 16 + t * 4);
                    s.x = fmaf(g4.x, wreg[t * 4 + 0].x, s.x);
                    s.y = fmaf(g4.x, wreg[t * 4 + 0].y, s.y);
                    s.z = fmaf(g4.x, wreg[t * 4 + 0].z, s.z);
                    s.w = fmaf(g4.x, wreg[t * 4 + 0].w, s.w);
                    s.x = fmaf(g4.y, wreg[t * 4 + 1].x, s.x);
                    s.y = fmaf(g4.y, wreg[t * 4 + 1].y, s.y);
                    s.z = fmaf(g4.y, wreg[t * 4 + 1].z, s.z);
                    s.w = fmaf(g4.y, wreg[t * 4 + 1].w, s.w);
                    s.x = fmaf(g4.z, wreg[t * 4 + 2].x, s.x);
                    s.y = fmaf(g4.z, wreg[t * 4 + 2].y, s.y);
                    s.z = fmaf(g4.z, wreg[t * 4 + 2].z, s.z);
                    s.w = fmaf(g4.z, wreg[t * 4 + 2].w, s.w);
                    s.x = fmaf(g4.w, wreg[t * 4 + 3].x, s.x);
                    s.y = fmaf(g4.w, wreg[t * 4 + 3].y, s.y);
                    s.z = fmaf(g4.w, wreg[t * 4 + 3].z, s.z);
                    s.w = fmaf(g4.w, wreg[t * 4 + 3].w, s.w);
                }
                float4 sg;
                sg.x = fsigmoid(s.x); sg.y = fsigmoid(s.y);
                sg.z = fsigmoid(s.z); sg.w = fsigmoid(s.w);
                float4 xj = *reinterpret_cast<const float4*>(xs + (bn + off) * NH + h4 * 4);
                acc.x = fmaf(sg.x, xj.x, acc.x);
                acc.y = fmaf(sg.y, xj.y, acc.y);
                acc.z = fmaf(sg.z, xj.z, acc.z);
                acc.w = fmaf(sg.w, xj.w, acc.w);
            }
        }
        *reinterpret_cast<float4*>(outsel + bn * NH + h4 * 4) = acc;
        __syncthreads();   // gg reused next batch
    }
}

extern "C" void kernel_launch(void* const* d_in, const int* in_sizes, int n_in,
                              void* d_out, int out_size, void* d_ws, size_t ws_size,
                              hipStream_t stream) {
    const float* xs   = (const float*)d_in[0];
    const float* vec  = (const float*)d_in[1];
    const float* Wg   = (const float*)d_in[2];
    const float* qw1  = (const float*)d_in[3];
    const float* qb1  = (const float*)d_in[4];
    const float* qw2  = (const float*)d_in[5];
    const float* qb2  = (const float*)d_in[6];
    const float* kw1  = (const float*)d_in[7];
    const float* kb1  = (const float*)d_in[8];
    const float* kw2  = (const float*)d_in[9];
    const float* kb2  = (const float*)d_in[10];
    const float* Wq   = (const float*)d_in[11];
    const float* bq   = (const float*)d_in[12];
    const float* Wk   = (const float*)d_in[13];
    const float* bk   = (const float*)d_in[14];

    float* vg = (float*)d_ws;                          // B*N*3*G floats
    float* u  = vg + (size_t)NB * NN * 3 * NG;
    float* outq = (float*)d_out;
    float* outk = outq + (size_t)NB * NN * NH;

    k_vecgeom<<<dim3(12288), dim3(256), 0, stream>>>(vec, Wg, vg);
    k_u<<<dim3(4096), dim3(256), 0, stream>>>(vg, u);
    k_main<<<dim3(2048), dim3(256), 0, stream>>>(
        vg, u, xs, qw1, qb1, qw2, qb2, kw1, kb1, kw2, kb2,
        Wq, bq, Wk, bk, outq, outk);
}

// Round 3
// 187.277 us; speedup vs baseline: 1.2193x; 1.2193x over previous
//
#include <hip/hip_runtime.h>

constexpr int NB = 8;
constexpr int NN = 8192;
constexpr int NH = 128;
constexpr int NG = 16;
constexpr float EPS = 1e-8f;
constexpr int NT = 48;            // table intervals per axis
constexpr int NT1 = NT + 1;       // 49 grid points
constexpr int NGRP = NB * NN / 4; // 16384 groups of 4 nodes

__device__ __forceinline__ float frcp(float x) { return __builtin_amdgcn_rcpf(x); }
__device__ __forceinline__ float fsqrt(float x) { return __builtin_amdgcn_sqrtf(x); }
__device__ __forceinline__ float fsigmoid(float x) { return frcp(1.f + __expf(-x)); }
__device__ __forceinline__ float fsilu(float x) { return x * fsigmoid(x); }
__device__ __forceinline__ float fclamp1(float x) { return fminf(fmaxf(x, -1.f), 1.f); }

// ---------------- K0: build 49x49 bilinear table of both gate MLPs ----------
__global__ __launch_bounds__(256) void k_table(
    const float* __restrict__ qw1, const float* __restrict__ qb1,
    const float* __restrict__ qw2, const float* __restrict__ qb2,
    const float* __restrict__ kw1, const float* __restrict__ kb1,
    const float* __restrict__ kw2, const float* __restrict__ kb2,
    float2* __restrict__ T) {
    int idx = blockIdx.x * 256 + threadIdx.x;
    if (idx >= NT1 * NT1) return;
    int ia = idx / NT1, id = idx % NT1;
    float a = -1.f + (float)ia * (2.f / NT);
    float d = -1.f + (float)id * (2.f / NT);
    float fq = qb2[0], fk = kb2[0];
#pragma unroll
    for (int m = 0; m < 16; ++m) {
        float hq = fmaf(a, qw1[m], fmaf(d, qw1[16 + m], qb1[m]));
        float hk = fmaf(a, kw1[m], fmaf(d, kw1[16 + m], kb1[m]));
        fq = fmaf(fsilu(hq), qw2[m], fq);
        fk = fmaf(fsilu(hk), kw2[m], fk);
    }
    T[idx] = make_float2(fq, fk);
}

// ---------------- K1: vec_geom = vec @ W_geom  (B*N*3, H) @ (H, G) ----------
__global__ __launch_bounds__(256) void k_vecgeom(const float* __restrict__ vec,
                                                 const float* __restrict__ Wg,
                                                 float* __restrict__ vg) {
    __shared__ float Wl[NH * NG];
    for (int t = threadIdx.x; t < NH * NG; t += 256) Wl[t] = Wg[t];
    __syncthreads();

    int idx = blockIdx.x * 256 + threadIdx.x;
    int node = idx / 48;
    int cg = idx % 48;
    int c = cg >> 4, g = cg & 15;
    const float* vrow = vec + (node * 3 + c) * NH;
    float acc = 0.f;
#pragma unroll 8
    for (int h = 0; h < NH; h += 4) {
        float4 v4 = *reinterpret_cast<const float4*>(vrow + h);
        acc = fmaf(v4.x, Wl[(h + 0) * NG + g], acc);
        acc = fmaf(v4.y, Wl[(h + 1) * NG + g], acc);
        acc = fmaf(v4.z, Wl[(h + 2) * NG + g], acc);
        acc = fmaf(v4.w, Wl[(h + 3) * NG + g], acc);
    }
    vg[(node * 3 + c) * NG + g] = acc;
}

// ---------------- K2: u[i] = sum_j normalize(vg[j]-vg[i]) -------------------
__global__ __launch_bounds__(256) void k_u(const float* __restrict__ vg,
                                           float* __restrict__ u) {
    int idx = blockIdx.x * 256 + threadIdx.x;
    int g = idx & 15;
    int bn = idx >> 4;
    int n = bn & (NN - 1);
    int base_i = (bn * 3) * NG + g;
    float vi0 = vg[base_i], vi1 = vg[base_i + NG], vi2 = vg[base_i + 2 * NG];
    float a0 = 0.f, a1 = 0.f, a2 = 0.f;
#pragma unroll
    for (int e = 0; e < 6; ++e) {
        int off = (e < 3) ? (e - 3) : (e - 2);
        int j = n + off;
        if (j < 0 || j >= NN) continue;
        int base_j = base_i + off * 3 * NG;
        float d0 = vg[base_j] - vi0;
        float d1 = vg[base_j + NG] - vi1;
        float d2 = vg[base_j + 2 * NG] - vi2;
        float nb = fmaxf(fsqrt(d0 * d0 + d1 * d1 + d2 * d2), EPS);
        float r = frcp(nb);
        a0 = fmaf(d0, r, a0); a1 = fmaf(d1, r, a1); a2 = fmaf(d2, r, a2);
    }
    u[base_i] = a0; u[base_i + NG] = a1; u[base_i + 2 * NG] = a2;
}

// ---------------- K3: barrier-free fused kernel -----------------------------
// 4 waves/block, each wave owns groups of 4 nodes end-to-end (grid-stride).
// Phase A: lane=(edge-group,g), geometry + table lookup -> gg in LDS.
// Phase B: lane=h (per qk/half round, fully unrolled), weights in 64 VGPRs.
// Same-wave LDS ops are in-order -> no __syncthreads in the loop.
__global__ __launch_bounds__(256) void k_main(
    const float* __restrict__ vg, const float* __restrict__ u,
    const float* __restrict__ xs, const float2* __restrict__ T,
    const float* __restrict__ Wq, const float* __restrict__ bq,
    const float* __restrict__ Wk, const float* __restrict__ bk,
    float* __restrict__ outq, float* __restrict__ outk) {
    __shared__ float2 Ts[NT1 * NT1];                 // 19.2 KB
    __shared__ __align__(16) float gg[2][4][4][6][16]; // [qk][wave][nb][e][g] 12 KB

    int tid = threadIdx.x;
    for (int t = tid; t < NT1 * NT1; t += 256) Ts[t] = T[t];

    int w = tid >> 6, lane = tid & 63;
    int eg = lane >> 4, g = lane & 15;

    // Register-resident gate weights: [qk][half][g]
    float wr[2][2][16];
#pragma unroll
    for (int gi = 0; gi < 16; ++gi) {
        wr[0][0][gi] = Wq[gi * NH + lane];
        wr[0][1][gi] = Wq[gi * NH + lane + 64];
        wr[1][0][gi] = Wk[gi * NH + lane];
        wr[1][1][gi] = Wk[gi * NH + lane + 64];
    }
    float bb[2][2] = {{bq[lane], bq[lane + 64]}, {bk[lane], bk[lane + 64]}};

    __syncthreads();   // table ready (only barrier)

    for (int grp = blockIdx.x * 4 + w; grp < NGRP; grp += gridDim.x * 4) {
        int bn0 = grp * 4;

        // ---- Phase A ----
#pragma unroll
        for (int nb = 0; nb < 4; ++nb) {
            int bn = bn0 + nb;
            int n = bn & (NN - 1);
            int base_i = (bn * 3) * NG + g;
            float vi0 = vg[base_i], vi1 = vg[base_i + NG], vi2 = vg[base_i + 2 * NG];
            float ui0 = u[base_i],  ui1 = u[base_i + NG],  ui2 = u[base_i + 2 * NG];
            float rnui = frcp(fmaxf(fsqrt(ui0 * ui0 + ui1 * ui1 + ui2 * ui2), EPS));

#pragma unroll
            for (int r = 0; r < 2; ++r) {
                int e = r * 4 + eg;
                if (e < 6) {
                    int off = (e < 3) ? (e - 3) : (e - 2);
                    int j = n + off;
                    if (j >= 0 && j < NN) {
                        int base_j = base_i + off * 3 * NG;
                        float d0 = vg[base_j] - vi0;
                        float d1 = vg[base_j + NG] - vi1;
                        float d2 = vg[base_j + 2 * NG] - vi2;
                        float rb = frcp(fmaxf(fsqrt(d0 * d0 + d1 * d1 + d2 * d2), EPS));
                        float e0 = d0 * rb, e1 = d1 * rb, e2 = d2 * rb;
                        float uj0 = u[base_j], uj1 = u[base_j + NG], uj2 = u[base_j + 2 * NG];
                        float die = ui0 * e0 + ui1 * e1 + ui2 * e2;
                        float ang = fclamp1(die * rnui);
                        float p0 = ui0 - die * e0, p1 = ui1 - die * e1, p2 = ui2 - die * e2;
                        float dje = uj0 * e0 + uj1 * e1 + uj2 * e2;
                        float q0 = uj0 - dje * e0, q1 = uj1 - dje * e1, q2 = uj2 - dje * e2;
                        float dp = p0 * q0 + p1 * q1 + p2 * q2;
                        float npi = fmaxf(fsqrt(p0 * p0 + p1 * p1 + p2 * p2), EPS);
                        float npj = fmaxf(fsqrt(q0 * q0 + q1 * q1 + q2 * q2), EPS);
                        float dih = fclamp1(dp * frcp(fmaxf(npi * npj, EPS)));

                        // bilinear table lookup (q and k together)
                        float af = fmaf(ang, (float)NT / 2.f, (float)NT / 2.f);
                        float df_ = fmaf(dih, (float)NT / 2.f, (float)NT / 2.f);
                        int ia = min((int)af, NT - 1);
                        int id = min((int)df_, NT - 1);
                        float fa = af - (float)ia;
                        float fd = df_ - (float)id;
                        const float2* t0 = &Ts[ia * NT1 + id];
                        float2 c00 = t0[0], c01 = t0[1];
                        float2 c10 = t0[NT1], c11 = t0[NT1 + 1];
                        float loq = fmaf(fd, c01.x - c00.x, c00.x);
                        float hiq = fmaf(fd, c11.x - c10.x, c10.x);
                        float lok = fmaf(fd, c01.y - c00.y, c00.y);
                        float hik = fmaf(fd, c11.y - c10.y, c10.y);
                        gg[0][w][nb][e][g] = fmaf(fa, hiq - loq, loq);
                        gg[1][w][nb][e][g] = fmaf(fa, hik - lok, lok);
                    }
                }
            }
        }
        asm volatile("" ::: "memory");  // compiler fence; DS is in-order per wave

        // ---- Phase B ----
#pragma unroll
        for (int nb = 0; nb < 4; ++nb) {
            int bn = bn0 + nb;
            int n = bn & (NN - 1);
#pragma unroll
            for (int qk = 0; qk < 2; ++qk) {
#pragma unroll
                for (int hf = 0; hf < 2; ++hf) {
                    float acc = 0.f;
#pragma unroll
                    for (int e = 0; e < 6; ++e) {
                        int off = (e < 3) ? (e - 3) : (e - 2);
                        int j = n + off;
                        if (j >= 0 && j < NN) {
                            const float* gp = &gg[qk][w][nb][e][0];
                            float4 g0 = *reinterpret_cast<const float4*>(gp);
                            float4 g1 = *reinterpret_cast<const float4*>(gp + 4);
                            float4 g2 = *reinterpret_cast<const float4*>(gp + 8);
                            float4 g3 = *reinterpret_cast<const float4*>(gp + 12);
                            float s = bb[qk][hf];
                            s = fmaf(g0.x, wr[qk][hf][0], s);
                            s = fmaf(g0.y, wr[qk][hf][1], s);
                            s = fmaf(g0.z, wr[qk][hf][2], s);
                            s = fmaf(g0.w, wr[qk][hf][3], s);
                            s = fmaf(g1.x, wr[qk][hf][4], s);
                            s = fmaf(g1.y, wr[qk][hf][5], s);
                            s = fmaf(g1.z, wr[qk][hf][6], s);
                            s = fmaf(g1.w, wr[qk][hf][7], s);
                            s = fmaf(g2.x, wr[qk][hf][8], s);
                            s = fmaf(g2.y, wr[qk][hf][9], s);
                            s = fmaf(g2.z, wr[qk][hf][10], s);
                            s = fmaf(g2.w, wr[qk][hf][11], s);
                            s = fmaf(g3.x, wr[qk][hf][12], s);
                            s = fmaf(g3.y, wr[qk][hf][13], s);
                            s = fmaf(g3.z, wr[qk][hf][14], s);
                            s = fmaf(g3.w, wr[qk][hf][15], s);
                            float xj = xs[(bn + off) * NH + hf * 64 + lane];
                            acc = fmaf(fsigmoid(s), xj, acc);
                        }
                    }
                    float* op = qk ? outk : outq;
                    op[bn * NH + hf * 64 + lane] = acc;
                }
            }
        }
        asm volatile("" ::: "memory");  // gg reused next group by same wave
    }
}

extern "C" void kernel_launch(void* const* d_in, const int* in_sizes, int n_in,
                              void* d_out, int out_size, void* d_ws, size_t ws_size,
                              hipStream_t stream) {
    const float* xs   = (const float*)d_in[0];
    const float* vec  = (const float*)d_in[1];
    const float* Wg   = (const float*)d_in[2];
    const float* qw1  = (const float*)d_in[3];
    const float* qb1  = (const float*)d_in[4];
    const float* qw2  = (const float*)d_in[5];
    const float* qb2  = (const float*)d_in[6];
    const float* kw1  = (const float*)d_in[7];
    const float* kb1  = (const float*)d_in[8];
    const float* kw2  = (const float*)d_in[9];
    const float* kb2  = (const float*)d_in[10];
    const float* Wq   = (const float*)d_in[11];
    const float* bq   = (const float*)d_in[12];
    const float* Wk   = (const float*)d_in[13];
    const float* bk   = (const float*)d_in[14];

    float* vg = (float*)d_ws;                          // B*N*3*G floats
    float* u  = vg + (size_t)NB * NN * 3 * NG;
    float2* T = (float2*)(u + (size_t)NB * NN * 3 * NG);
    float* outq = (float*)d_out;
    float* outk = outq + (size_t)NB * NN * NH;

    k_table<<<dim3((NT1 * NT1 + 255) / 256), dim3(256), 0, stream>>>(
        qw1, qb1, qw2, qb2, kw1, kb1, kw2, kb2, T);
    k_vecgeom<<<dim3(12288), dim3(256), 0, stream>>>(vec, Wg, vg);
    k_u<<<dim3(4096), dim3(256), 0, stream>>>(vg, u);
    k_main<<<dim3(2048), dim3(256), 0, stream>>>(
        vg, u, xs, T, Wq, bq, Wk, bk, outq, outk);
}

// Round 5
// 140.126 us; speedup vs baseline: 1.6295x; 1.3365x over previous
//
#include <hip/hip_runtime.h>

constexpr int NB = 8;
constexpr int NN = 8192;
constexpr int NH = 128;
constexpr int NG = 16;
constexpr float EPS = 1e-8f;
constexpr int NT = 48;            // table intervals per axis
constexpr int NT1 = NT + 1;       // 49 grid points
constexpr int NGRP = NB * NN / 4; // 16384 groups of 4 nodes

typedef _Float16 half2v __attribute__((ext_vector_type(2)));

__device__ __forceinline__ float frcp(float x) { return __builtin_amdgcn_rcpf(x); }
__device__ __forceinline__ float fsqrt(float x) { return __builtin_amdgcn_sqrtf(x); }
__device__ __forceinline__ float fsigmoid(float x) { return frcp(1.f + __expf(-x)); }
__device__ __forceinline__ float fsilu(float x) { return x * fsigmoid(x); }
__device__ __forceinline__ float fclamp1(float x) { return fminf(fmaxf(x, -1.f), 1.f); }
// sigmoid given NEGATED logit: 1/(1+e^{sneg})
__device__ __forceinline__ float fsigmoid_neg(float sneg) { return frcp(1.f + __expf(sneg)); }

__device__ __forceinline__ half2v mkh2(float a, float b) {
#if __has_builtin(__builtin_amdgcn_cvt_pkrtz)
    return __builtin_bit_cast(half2v, __builtin_amdgcn_cvt_pkrtz(a, b));
#else
    half2v h; h.x = (_Float16)a; h.y = (_Float16)b; return h;
#endif
}
__device__ __forceinline__ float fdot2(half2v a, half2v b, float c) {
#if __has_builtin(__builtin_amdgcn_fdot2)
    return __builtin_amdgcn_fdot2(a, b, c, false);
#else
    return c + (float)a.x * (float)b.x + (float)a.y * (float)b.y;
#endif
}
__device__ __forceinline__ half2v ash2(float f) { return __builtin_bit_cast(half2v, f); }

// ---------------- K0: build 49x49 bilinear table of both gate MLPs ----------
__global__ __launch_bounds__(256) void k_table(
    const float* __restrict__ qw1, const float* __restrict__ qb1,
    const float* __restrict__ qw2, const float* __restrict__ qb2,
    const float* __restrict__ kw1, const float* __restrict__ kb1,
    const float* __restrict__ kw2, const float* __restrict__ kb2,
    float2* __restrict__ T) {
    int idx = blockIdx.x * 256 + threadIdx.x;
    if (idx >= NT1 * NT1) return;
    int ia = idx / NT1, id = idx % NT1;
    float a = -1.f + (float)ia * (2.f / NT);
    float d = -1.f + (float)id * (2.f / NT);
    float fq = qb2[0], fk = kb2[0];
#pragma unroll
    for (int m = 0; m < 16; ++m) {
        float hq = fmaf(a, qw1[m], fmaf(d, qw1[16 + m], qb1[m]));
        float hk = fmaf(a, kw1[m], fmaf(d, kw1[16 + m], kb1[m]));
        fq = fmaf(fsilu(hq), qw2[m], fq);
        fk = fmaf(fsilu(hk), kw2[m], fk);
    }
    T[idx] = make_float2(fq, fk);
}

// ---------------- K1: vec_geom = vec @ W_geom -------------------------------
__global__ __launch_bounds__(256) void k_vecgeom(const float* __restrict__ vec,
                                                 const float* __restrict__ Wg,
                                                 float* __restrict__ vg) {
    __shared__ float Wl[NH * NG];
    for (int t = threadIdx.x; t < NH * NG; t += 256) Wl[t] = Wg[t];
    __syncthreads();

    int idx = blockIdx.x * 256 + threadIdx.x;
    int node = idx / 48;
    int cg = idx % 48;
    int c = cg >> 4, g = cg & 15;
    const float* vrow = vec + (node * 3 + c) * NH;
    float acc = 0.f;
#pragma unroll 8
    for (int h = 0; h < NH; h += 4) {
        float4 v4 = *reinterpret_cast<const float4*>(vrow + h);
        acc = fmaf(v4.x, Wl[(h + 0) * NG + g], acc);
        acc = fmaf(v4.y, Wl[(h + 1) * NG + g], acc);
        acc = fmaf(v4.z, Wl[(h + 2) * NG + g], acc);
        acc = fmaf(v4.w, Wl[(h + 3) * NG + g], acc);
    }
    vg[(node * 3 + c) * NG + g] = acc;
}

// ---------------- K2: u[i] = sum_j normalize(vg[j]-vg[i]) -------------------
__global__ __launch_bounds__(256) void k_u(const float* __restrict__ vg,
                                           float* __restrict__ u) {
    int idx = blockIdx.x * 256 + threadIdx.x;
    int g = idx & 15;
    int bn = idx >> 4;
    int n = bn & (NN - 1);
    int base_i = (bn * 3) * NG + g;
    float vi0 = vg[base_i], vi1 = vg[base_i + NG], vi2 = vg[base_i + 2 * NG];
    float a0 = 0.f, a1 = 0.f, a2 = 0.f;
#pragma unroll
    for (int e = 0; e < 6; ++e) {
        int off = (e < 3) ? (e - 3) : (e - 2);
        int j = n + off;
        if (j < 0 || j >= NN) continue;
        int base_j = base_i + off * 3 * NG;
        float d0 = vg[base_j] - vi0;
        float d1 = vg[base_j + NG] - vi1;
        float d2 = vg[base_j + 2 * NG] - vi2;
        float nb = fmaxf(fsqrt(d0 * d0 + d1 * d1 + d2 * d2), EPS);
        float r = frcp(nb);
        a0 = fmaf(d0, r, a0); a1 = fmaf(d1, r, a1); a2 = fmaf(d2, r, a2);
    }
    u[base_i] = a0; u[base_i + NG] = a1; u[base_i + 2 * NG] = a2;
}

// ---------------- K3 group worker -------------------------------------------
template <bool INT>
__device__ __forceinline__ void do_group(
    int bn0, int n0, int w, int eg, int g, int lane,
    const float* __restrict__ vg, const float* __restrict__ u,
    const float* __restrict__ xs, const float2 (&Ts)[NT1 * NT1],
    half2v (&gg)[2][4][4][6][8],
    const half2v (&wneg)[2][2][8], const float (&bneg)[2][2],
    float* __restrict__ outq, float* __restrict__ outk) {

    // ---- Phase A: per-edge geometry + table lookup -> packed f16 gates ----
#pragma unroll
    for (int nb = 0; nb < 4; ++nb) {
        int bn = bn0 + nb;
        int base_i = (bn * 3) * NG + g;
        float vi0 = vg[base_i], vi1 = vg[base_i + NG], vi2 = vg[base_i + 2 * NG];
        float ui0 = u[base_i],  ui1 = u[base_i + NG],  ui2 = u[base_i + 2 * NG];
        float rnui = frcp(fmaxf(fsqrt(ui0 * ui0 + ui1 * ui1 + ui2 * ui2), EPS));

#pragma unroll
        for (int r = 0; r < 2; ++r) {
            int e = r * 4 + eg;
            if (e < 6) {
                int off = (e < 3) ? (e - 3) : (e - 2);
                bool valid = INT || ((n0 + nb + off) >= 0 && (n0 + nb + off) < NN);
                float fq = 0.f, fk = 0.f;
                if (valid) {
                    int base_j = base_i + off * 3 * NG;
                    float d0 = vg[base_j] - vi0;
                    float d1 = vg[base_j + NG] - vi1;
                    float d2 = vg[base_j + 2 * NG] - vi2;
                    float rb = frcp(fmaxf(fsqrt(d0 * d0 + d1 * d1 + d2 * d2), EPS));
                    float e0 = d0 * rb, e1 = d1 * rb, e2 = d2 * rb;
                    float uj0 = u[base_j], uj1 = u[base_j + NG], uj2 = u[base_j + 2 * NG];
                    float die = ui0 * e0 + ui1 * e1 + ui2 * e2;
                    float ang = fclamp1(die * rnui);
                    float p0 = ui0 - die * e0, p1 = ui1 - die * e1, p2 = ui2 - die * e2;
                    float dje = uj0 * e0 + uj1 * e1 + uj2 * e2;
                    float q0 = uj0 - dje * e0, q1 = uj1 - dje * e1, q2 = uj2 - dje * e2;
                    float dp = p0 * q0 + p1 * q1 + p2 * q2;
                    float npi = fmaxf(fsqrt(p0 * p0 + p1 * p1 + p2 * p2), EPS);
                    float npj = fmaxf(fsqrt(q0 * q0 + q1 * q1 + q2 * q2), EPS);
                    float dih = fclamp1(dp * frcp(fmaxf(npi * npj, EPS)));

                    float af = fmaf(ang, (float)NT / 2.f, (float)NT / 2.f);
                    float df_ = fmaf(dih, (float)NT / 2.f, (float)NT / 2.f);
                    int ia = min((int)af, NT - 1);
                    int id = min((int)df_, NT - 1);
                    float fa = af - (float)ia;
                    float fd = df_ - (float)id;
                    const float2* t0 = &Ts[ia * NT1 + id];
                    float2 c00 = t0[0], c01 = t0[1];
                    float2 c10 = t0[NT1], c11 = t0[NT1 + 1];
                    float loq = fmaf(fd, c01.x - c00.x, c00.x);
                    float hiq = fmaf(fd, c11.x - c10.x, c10.x);
                    float lok = fmaf(fd, c01.y - c00.y, c00.y);
                    float hik = fmaf(fd, c11.y - c10.y, c10.y);
                    fq = fmaf(fa, hiq - loq, loq);
                    fk = fmaf(fa, hik - lok, lok);
                }
                // pack (g even, g odd) -> half2; even-g lanes write
                float fq1 = __shfl_xor(fq, 1);
                float fk1 = __shfl_xor(fk, 1);
                if (!(g & 1)) {
                    gg[0][w][nb][e][g >> 1] = mkh2(fq, fq1);
                    gg[1][w][nb][e][g >> 1] = mkh2(fk, fk1);
                }
            }
        }
    }
    asm volatile("" ::: "memory");  // same-wave DS ordering; compiler fence

    // ---- Phase B: f16-dot gate + sigmoid + gather of x ----
    float xr[2][10];
    if (INT) {
#pragma unroll
        for (int d = 0; d < 10; ++d) {
            xr[0][d] = xs[(bn0 - 3 + d) * NH + lane];
            xr[1][d] = xs[(bn0 - 3 + d) * NH + lane + 64];
        }
    }
#pragma unroll
    for (int nb = 0; nb < 4; ++nb) {
        int bn = bn0 + nb;
#pragma unroll
        for (int qk = 0; qk < 2; ++qk) {
            float a0 = 0.f, a1 = 0.f;
#pragma unroll
            for (int e = 0; e < 6; ++e) {
                int off = (e < 3) ? (e - 3) : (e - 2);
                if (!INT) { int j = (n0 + nb) + off; if (j < 0 || j >= NN) continue; }
                const float4* gp = reinterpret_cast<const float4*>(&gg[qk][w][nb][e][0]);
                float4 r0 = gp[0], r1 = gp[1];
                float s0 = bneg[qk][0], s1 = bneg[qk][1];
                s0 = fdot2(ash2(r0.x), wneg[qk][0][0], s0);
                s0 = fdot2(ash2(r0.y), wneg[qk][0][1], s0);
                s0 = fdot2(ash2(r0.z), wneg[qk][0][2], s0);
                s0 = fdot2(ash2(r0.w), wneg[qk][0][3], s0);
                s0 = fdot2(ash2(r1.x), wneg[qk][0][4], s0);
                s0 = fdot2(ash2(r1.y), wneg[qk][0][5], s0);
                s0 = fdot2(ash2(r1.z), wneg[qk][0][6], s0);
                s0 = fdot2(ash2(r1.w), wneg[qk][0][7], s0);
                s1 = fdot2(ash2(r0.x), wneg[qk][1][0], s1);
                s1 = fdot2(ash2(r0.y), wneg[qk][1][1], s1);
                s1 = fdot2(ash2(r0.z), wneg[qk][1][2], s1);
                s1 = fdot2(ash2(r0.w), wneg[qk][1][3], s1);
                s1 = fdot2(ash2(r1.x), wneg[qk][1][4], s1);
                s1 = fdot2(ash2(r1.y), wneg[qk][1][5], s1);
                s1 = fdot2(ash2(r1.z), wneg[qk][1][6], s1);
                s1 = fdot2(ash2(r1.w), wneg[qk][1][7], s1);
                float p0 = fsigmoid_neg(s0);
                float p1 = fsigmoid_neg(s1);
                float x0, x1;
                if (INT) { x0 = xr[0][nb + off + 3]; x1 = xr[1][nb + off + 3]; }
                else { x0 = xs[(bn + off) * NH + lane]; x1 = xs[(bn + off) * NH + lane + 64]; }
                a0 = fmaf(p0, x0, a0);
                a1 = fmaf(p1, x1, a1);
            }
            float* op = qk ? outk : outq;
            op[bn * NH + lane] = a0;
            op[bn * NH + lane + 64] = a1;
        }
    }
    asm volatile("" ::: "memory");  // gg reused next group by same wave
}

// ---------------- K3: barrier-free fused kernel -----------------------------
__global__ __launch_bounds__(256) void k_main(
    const float* __restrict__ vg, const float* __restrict__ u,
    const float* __restrict__ xs, const float2* __restrict__ T,
    const float* __restrict__ Wq, const float* __restrict__ bq,
    const float* __restrict__ Wk, const float* __restrict__ bk,
    float* __restrict__ outq, float* __restrict__ outk) {
    __shared__ float2 Ts[NT1 * NT1];                    // 19.2 KB
    __shared__ __align__(16) half2v gg[2][4][4][6][8];  // 6 KB packed f16 gates

    int tid = threadIdx.x;
    for (int t = tid; t < NT1 * NT1; t += 256) Ts[t] = T[t];

    int w = tid >> 6, lane = tid & 63;
    int eg = lane >> 4, g = lane & 15;

    // Register-resident NEGATED f16 gate weights: wneg[qk][hf][t]=(−W[2t],−W[2t+1])
    half2v wneg[2][2][8];
    float bneg[2][2];
#pragma unroll
    for (int t = 0; t < 8; ++t) {
        wneg[0][0][t] = mkh2(-Wq[(2 * t) * NH + lane],      -Wq[(2 * t + 1) * NH + lane]);
        wneg[0][1][t] = mkh2(-Wq[(2 * t) * NH + lane + 64], -Wq[(2 * t + 1) * NH + lane + 64]);
        wneg[1][0][t] = mkh2(-Wk[(2 * t) * NH + lane],      -Wk[(2 * t + 1) * NH + lane]);
        wneg[1][1][t] = mkh2(-Wk[(2 * t) * NH + lane + 64], -Wk[(2 * t + 1) * NH + lane + 64]);
    }
    bneg[0][0] = -bq[lane]; bneg[0][1] = -bq[lane + 64];
    bneg[1][0] = -bk[lane]; bneg[1][1] = -bk[lane + 64];

    __syncthreads();   // table ready (only barrier)

    for (int grp = blockIdx.x * 4 + w; grp < NGRP; grp += gridDim.x * 4) {
        int bn0 = grp * 4;
        int n0 = bn0 & (NN - 1);
        bool interior = (n0 >= 4) && (n0 <= NN - 8);
        if (interior)
            do_group<true>(bn0, n0, w, eg, g, lane, vg, u, xs, Ts, gg, wneg, bneg, outq, outk);
        else
            do_group<false>(bn0, n0, w, eg, g, lane, vg, u, xs, Ts, gg, wneg, bneg, outq, outk);
    }
}

extern "C" void kernel_launch(void* const* d_in, const int* in_sizes, int n_in,
                              void* d_out, int out_size, void* d_ws, size_t ws_size,
                              hipStream_t stream) {
    const float* xs   = (const float*)d_in[0];
    const float* vec  = (const float*)d_in[1];
    const float* Wg   = (const float*)d_in[2];
    const float* qw1  = (const float*)d_in[3];
    const float* qb1  = (const float*)d_in[4];
    const float* qw2  = (const float*)d_in[5];
    const float* qb2  = (const float*)d_in[6];
    const float* kw1  = (const float*)d_in[7];
    const float* kb1  = (const float*)d_in[8];
    const float* kw2  = (const float*)d_in[9];
    const float* kb2  = (const float*)d_in[10];
    const float* Wq   = (const float*)d_in[11];
    const float* bq   = (const float*)d_in[12];
    const float* Wk   = (const float*)d_in[13];
    const float* bk   = (const float*)d_in[14];

    float* vg = (float*)d_ws;                          // B*N*3*G floats
    float* u  = vg + (size_t)NB * NN * 3 * NG;
    float2* T = (float2*)(u + (size_t)NB * NN * 3 * NG);
    float* outq = (float*)d_out;
    float* outk = outq + (size_t)NB * NN * NH;

    k_table<<<dim3((NT1 * NT1 + 255) / 256), dim3(256), 0, stream>>>(
        qw1, qb1, qw2, qb2, kw1, kb1, kw2, kb2, T);
    k_vecgeom<<<dim3(12288), dim3(256), 0, stream>>>(vec, Wg, vg);
    k_u<<<dim3(4096), dim3(256), 0, stream>>>(vg, u);
    k_main<<<dim3(2048), dim3(256), 0, stream>>>(
        vg, u, xs, T, Wq, bq, Wk, bk, outq, outk);
}

// Round 6
// 94.217 us; speedup vs baseline: 2.4235x; 1.4873x over previous
//
#include <hip/hip_runtime.h>

constexpr int NB = 8;
constexpr int NN = 8192;
constexpr int NH = 128;
constexpr int NG = 16;
constexpr float EPS = 1e-8f;
constexpr int NT = 48;            // table intervals per axis
constexpr int NT1 = NT + 1;       // 49 grid points

typedef short s16x8 __attribute__((ext_vector_type(8)));
typedef float f32x4 __attribute__((ext_vector_type(4)));

__device__ __forceinline__ float frcp(float x) { return __builtin_amdgcn_rcpf(x); }
__device__ __forceinline__ float frsq(float x) { return __builtin_amdgcn_rsqf(x); }
__device__ __forceinline__ float fsigmoid(float x) { return frcp(1.f + __expf(-x)); }
__device__ __forceinline__ float fsilu(float x) { return x * fsigmoid(x); }
__device__ __forceinline__ float fclamp1(float x) { return fminf(fmaxf(x, -1.f), 1.f); }

__device__ __forceinline__ unsigned short f2bf(float x) {  // f32 -> bf16 RTNE
    unsigned u = __builtin_bit_cast(unsigned, x);
    return (unsigned short)((u + 0x7FFFu + ((u >> 16) & 1u)) >> 16);
}
__device__ __forceinline__ unsigned packh2(float a, float b) {
    unsigned short lo = __builtin_bit_cast(unsigned short, (__fp16)a);
    unsigned short hi = __builtin_bit_cast(unsigned short, (__fp16)b);
    return (unsigned)lo | ((unsigned)hi << 16);
}
__device__ __forceinline__ float h2lo(unsigned u) {
    return (float)__builtin_bit_cast(__fp16, (unsigned short)(u & 0xFFFFu));
}
__device__ __forceinline__ float h2hi(unsigned u) {
    return (float)__builtin_bit_cast(__fp16, (unsigned short)(u >> 16));
}

// ---------------- K0: build 49x49 bilinear table of both gate MLPs ----------
__global__ __launch_bounds__(256) void k_table(
    const float* __restrict__ qw1, const float* __restrict__ qb1,
    const float* __restrict__ qw2, const float* __restrict__ qb2,
    const float* __restrict__ kw1, const float* __restrict__ kb1,
    const float* __restrict__ kw2, const float* __restrict__ kb2,
    unsigned* __restrict__ T) {
    int idx = blockIdx.x * 256 + threadIdx.x;
    if (idx >= NT1 * NT1) return;
    int ia = idx / NT1, id = idx % NT1;
    float a = -1.f + (float)ia * (2.f / NT);
    float d = -1.f + (float)id * (2.f / NT);
    float fq = qb2[0], fk = kb2[0];
#pragma unroll
    for (int m = 0; m < 16; ++m) {
        float hq = fmaf(a, qw1[m], fmaf(d, qw1[16 + m], qb1[m]));
        float hk = fmaf(a, kw1[m], fmaf(d, kw1[16 + m], kb1[m]));
        fq = fmaf(fsilu(hq), qw2[m], fq);
        fk = fmaf(fsilu(hk), kw2[m], fk);
    }
    T[idx] = packh2(fq, fk);
}

// ---------------- K1: vec_geom = vec @ W_geom (4 g-outputs per thread) ------
__global__ __launch_bounds__(256) void k_vecgeom(const float* __restrict__ vec,
                                                 const float* __restrict__ Wg,
                                                 float* __restrict__ vg) {
    __shared__ float Wl[NH * NG];
    for (int t = threadIdx.x; t < NH * NG; t += 256) Wl[t] = Wg[t];
    __syncthreads();

    int idx = blockIdx.x * 256 + threadIdx.x;   // 0 .. B*N*3*4 (exact grid)
    int gq = idx & 3;
    int rc = idx >> 2;                          // row = node*3+c
    const float4* vrow = reinterpret_cast<const float4*>(vec + rc * NH);
    float a0 = 0.f, a1 = 0.f, a2 = 0.f, a3 = 0.f;
#pragma unroll 8
    for (int h4 = 0; h4 < 32; ++h4) {
        float4 v = vrow[h4];
        int h = h4 * 4;
        float4 w0 = *reinterpret_cast<const float4*>(&Wl[(h + 0) * NG + gq * 4]);
        float4 w1 = *reinterpret_cast<const float4*>(&Wl[(h + 1) * NG + gq * 4]);
        float4 w2 = *reinterpret_cast<const float4*>(&Wl[(h + 2) * NG + gq * 4]);
        float4 w3 = *reinterpret_cast<const float4*>(&Wl[(h + 3) * NG + gq * 4]);
        a0 = fmaf(v.x, w0.x, a0); a1 = fmaf(v.x, w0.y, a1); a2 = fmaf(v.x, w0.z, a2); a3 = fmaf(v.x, w0.w, a3);
        a0 = fmaf(v.y, w1.x, a0); a1 = fmaf(v.y, w1.y, a1); a2 = fmaf(v.y, w1.z, a2); a3 = fmaf(v.y, w1.w, a3);
        a0 = fmaf(v.z, w2.x, a0); a1 = fmaf(v.z, w2.y, a1); a2 = fmaf(v.z, w2.z, a2); a3 = fmaf(v.z, w2.w, a3);
        a0 = fmaf(v.w, w3.x, a0); a1 = fmaf(v.w, w3.y, a1); a2 = fmaf(v.w, w3.z, a2); a3 = fmaf(v.w, w3.w, a3);
    }
    *reinterpret_cast<float4*>(vg + rc * NG + gq * 4) = make_float4(a0, a1, a2, a3);
}

// ---------------- K2: u[i] = sum_j normalize(vg[j]-vg[i]) -------------------
__global__ __launch_bounds__(256) void k_u(const float* __restrict__ vg,
                                           float* __restrict__ u) {
    int idx = blockIdx.x * 256 + threadIdx.x;
    int g = idx & 15;
    int bn = idx >> 4;
    int n = bn & (NN - 1);
    int base_i = bn * 48 + g;
    float vi0 = vg[base_i], vi1 = vg[base_i + 16], vi2 = vg[base_i + 32];
    float a0 = 0.f, a1 = 0.f, a2 = 0.f;
#pragma unroll
    for (int e = 0; e < 6; ++e) {
        int off = (e < 3) ? (e - 3) : (e - 2);
        int j = n + off;
        if (j < 0 || j >= NN) continue;
        int base_j = base_i + off * 48;
        float d0 = vg[base_j] - vi0;
        float d1 = vg[base_j + 16] - vi1;
        float d2 = vg[base_j + 32] - vi2;
        float r = frsq(fmaxf(d0 * d0 + d1 * d1 + d2 * d2, 1e-16f));
        a0 = fmaf(d0, r, a0); a1 = fmaf(d1, r, a1); a2 = fmaf(d2, r, a2);
    }
    u[base_i] = a0; u[base_i + 16] = a1; u[base_i + 32] = a2;
}

// ---------------- K3 per-group worker (16 nodes per wave) -------------------
template <bool INT>
__device__ __forceinline__ void run_group(
    int bn0, int n0, int w, int lane,
    const float* __restrict__ vg, const float* __restrict__ u,
    const float* __restrict__ xs, const unsigned (&Ts)[NT1 * NT1],
    unsigned short (&As)[4][2][6][16][16], const s16x8 (&Wl)[2][8][64],
    const float (&bneg)[16],
    float* __restrict__ outq, float* __restrict__ outk) {

    int nl = lane >> 4, g = lane & 15;

    // ---- Phase A: geometry + table -> bf16 gates in A-fragment layout ----
#pragma unroll
    for (int nq = 0; nq < 4; ++nq) {
        int node = nq * 4 + nl;
        int bn = bn0 + node;
        int base_i = bn * 48 + g;
        float vi0 = vg[base_i], vi1 = vg[base_i + 16], vi2 = vg[base_i + 32];
        float ui0 = u[base_i],  ui1 = u[base_i + 16],  ui2 = u[base_i + 32];
        float rnui = frsq(fmaxf(ui0 * ui0 + ui1 * ui1 + ui2 * ui2, 1e-16f));
#pragma unroll
        for (int e = 0; e < 6; ++e) {
            int off = (e < 3) ? (e - 3) : (e - 2);
            bool valid = INT || ((unsigned)(n0 + node + off) < (unsigned)NN);
            float fq = 0.f, fk = 0.f;
            if (valid) {
                int base_j = base_i + off * 48;
                float d0 = vg[base_j] - vi0;
                float d1 = vg[base_j + 16] - vi1;
                float d2 = vg[base_j + 32] - vi2;
                float rb = frsq(fmaxf(d0 * d0 + d1 * d1 + d2 * d2, 1e-16f));
                float e0 = d0 * rb, e1 = d1 * rb, e2 = d2 * rb;
                float uj0 = u[base_j], uj1 = u[base_j + 16], uj2 = u[base_j + 32];
                float die = ui0 * e0 + ui1 * e1 + ui2 * e2;
                float ang = fclamp1(die * rnui);
                float p0 = ui0 - die * e0, p1 = ui1 - die * e1, p2 = ui2 - die * e2;
                float dje = uj0 * e0 + uj1 * e1 + uj2 * e2;
                float q0 = uj0 - dje * e0, q1 = uj1 - dje * e1, q2 = uj2 - dje * e2;
                float dp = p0 * q0 + p1 * q1 + p2 * q2;
                float pp = fmaxf(p0 * p0 + p1 * p1 + p2 * p2, 1e-16f);
                float qq = fmaxf(q0 * q0 + q1 * q1 + q2 * q2, 1e-16f);
                float dih = fclamp1(dp * frsq(pp * qq));

                float af = fmaf(ang, (float)NT * 0.5f, (float)NT * 0.5f);
                float df_ = fmaf(dih, (float)NT * 0.5f, (float)NT * 0.5f);
                int ia = min((int)af, NT - 1);
                int id = min((int)df_, NT - 1);
                float fa = af - (float)ia;
                float fd = df_ - (float)id;
                const unsigned* t0 = &Ts[ia * NT1 + id];
                unsigned c00 = t0[0], c01 = t0[1], c10 = t0[NT1], c11 = t0[NT1 + 1];
                float l0q = fmaf(fd, h2lo(c01) - h2lo(c00), h2lo(c00));
                float h0q = fmaf(fd, h2lo(c11) - h2lo(c10), h2lo(c10));
                fq = fmaf(fa, h0q - l0q, l0q);
                float l0k = fmaf(fd, h2hi(c01) - h2hi(c00), h2hi(c00));
                float h0k = fmaf(fd, h2hi(c11) - h2hi(c10), h2hi(c10));
                fk = fmaf(fa, h0k - l0k, l0k);
            }
            As[w][0][e][node][g] = f2bf(fq);
            As[w][1][e][node][g] = f2bf(fk);
        }
    }
    asm volatile("" ::: "memory");  // same-wave DS in-order; stop reordering

    // ---- A-fragments: lane<32 reads [row=lane&15][k=(lane>>4)*8+i] ----
    s16x8 afr[2][6];
    int aidx = (lane & 15) * 2 + (lane >> 4);
#pragma unroll
    for (int qk = 0; qk < 2; ++qk)
#pragma unroll
        for (int e = 0; e < 6; ++e)
            afr[qk][e] = (lane < 32)
                ? reinterpret_cast<const s16x8*>(&As[w][qk][e][0][0])[aidx]
                : (s16x8)0;

    // ---- Phase B: MFMA logits + sigmoid gate + x fma, accumulate over e ----
    const float* xw = xs + (bn0 + (lane >> 4) * 4) * NH + (lane & 15);
    float* oq = outq + (bn0 + (lane >> 4) * 4) * NH + (lane & 15);
    float* ok = outk + (bn0 + (lane >> 4) * 4) * NH + (lane & 15);
    f32x4 zero4 = {0.f, 0.f, 0.f, 0.f};

#pragma unroll
    for (int qk = 0; qk < 2; ++qk) {
#pragma unroll
        for (int ht = 0; ht < 8; ++ht) {
            s16x8 bfr = Wl[qk][ht][lane];
            f32x4 acc = zero4;
            float bn_ = bneg[qk * 8 + ht];
#pragma unroll
            for (int e = 0; e < 6; ++e) {
                f32x4 c = __builtin_amdgcn_mfma_f32_16x16x32_bf16(
                    afr[qk][e], bfr, zero4, 0, 0, 0);
                int off = (e < 3) ? (e - 3) : (e - 2);
                const float* xp = xw + off * NH + ht * 16;
#pragma unroll
                for (int r = 0; r < 4; ++r) {
                    float sneg = bn_ - c[r];
                    float p = frcp(1.f + __expf(sneg));
                    float xv;
                    if (INT) {
                        xv = xp[r * NH];
                    } else {
                        int jn = n0 + (lane >> 4) * 4 + r + off;
                        bool v2 = (unsigned)jn < (unsigned)NN;
                        const float* xq = v2 ? (xp + r * NH) : xs;
                        xv = *xq;
                        p = v2 ? p : 0.f;
                    }
                    acc[r] = fmaf(p, xv, acc[r]);
                }
            }
            float* o = (qk ? ok : oq) + ht * 16;
#pragma unroll
            for (int r = 0; r < 4; ++r) o[r * NH] = acc[r];
        }
    }
    asm volatile("" ::: "memory");
}

// ---------------- K3: fused kernel, 16 nodes/wave, MFMA Phase B -------------
__global__ __launch_bounds__(256) void k_main(
    const float* __restrict__ vg, const float* __restrict__ u,
    const float* __restrict__ xs, const unsigned* __restrict__ T,
    const float* __restrict__ Wq, const float* __restrict__ bq,
    const float* __restrict__ Wk, const float* __restrict__ bk,
    float* __restrict__ outq, float* __restrict__ outk) {
    __shared__ unsigned Ts[NT1 * NT1];              // 9.6 KB (f16-pair table)
    __shared__ unsigned short As[4][2][6][16][16];  // 24 KB  (bf16 A tiles)
    __shared__ s16x8 Wl[2][8][64];                  // 16 KB  (B fragments)

    int tid = threadIdx.x;
    for (int t = tid; t < NT1 * NT1; t += 256) Ts[t] = T[t];

    // build B-fragments: B[k=g][col=h]; lanes>=32 (k>=16 pad) are zero
    for (int slot = tid; slot < 2 * 8 * 64; slot += 256) {
        int lane_in = slot & 63;
        int frag = slot >> 6;
        int fqk = frag >> 3, fht = frag & 7;
        s16x8 v = (s16x8)0;
        if (lane_in < 32) {
            const float* W = fqk ? Wk : Wq;
            int k0 = (lane_in >> 4) * 8, fcol = lane_in & 15;
#pragma unroll
            for (int i = 0; i < 8; ++i)
                v[i] = (short)f2bf(W[(k0 + i) * NH + fht * 16 + fcol]);
        }
        Wl[fqk][fht][lane_in] = v;
    }

    int w = tid >> 6, lane = tid & 63;
    int col = lane & 15;
    float bneg[16];
#pragma unroll
    for (int ht = 0; ht < 8; ++ht) {
        bneg[ht]     = -bq[ht * 16 + col];
        bneg[8 + ht] = -bk[ht * 16 + col];
    }
    __syncthreads();

    int grp = blockIdx.x * 4 + w;     // 4096 groups of 16 nodes (exact grid)
    int bn0 = grp * 16;
    int n0 = bn0 & (NN - 1);
    bool interior = (n0 != 0) && (n0 != NN - 16);
    if (interior)
        run_group<true>(bn0, n0, w, lane, vg, u, xs, Ts, As, Wl, bneg, outq, outk);
    else
        run_group<false>(bn0, n0, w, lane, vg, u, xs, Ts, As, Wl, bneg, outq, outk);
}

extern "C" void kernel_launch(void* const* d_in, const int* in_sizes, int n_in,
                              void* d_out, int out_size, void* d_ws, size_t ws_size,
                              hipStream_t stream) {
    const float* xs   = (const float*)d_in[0];
    const float* vec  = (const float*)d_in[1];
    const float* Wg   = (const float*)d_in[2];
    const float* qw1  = (const float*)d_in[3];
    const float* qb1  = (const float*)d_in[4];
    const float* qw2  = (const float*)d_in[5];
    const float* qb2  = (const float*)d_in[6];
    const float* kw1  = (const float*)d_in[7];
    const float* kb1  = (const float*)d_in[8];
    const float* kw2  = (const float*)d_in[9];
    const float* kb2  = (const float*)d_in[10];
    const float* Wq   = (const float*)d_in[11];
    const float* bq   = (const float*)d_in[12];
    const float* Wk   = (const float*)d_in[13];
    const float* bk   = (const float*)d_in[14];

    float* vg = (float*)d_ws;                          // B*N*3*G floats
    float* u  = vg + (size_t)NB * NN * 3 * NG;
    unsigned* T = (unsigned*)(u + (size_t)NB * NN * 3 * NG);
    float* outq = (float*)d_out;
    float* outk = outq + (size_t)NB * NN * NH;

    k_table<<<dim3((NT1 * NT1 + 255) / 256), dim3(256), 0, stream>>>(
        qw1, qb1, qw2, qb2, kw1, kb1, kw2, kb2, T);
    k_vecgeom<<<dim3(3072), dim3(256), 0, stream>>>(vec, Wg, vg);
    k_u<<<dim3(4096), dim3(256), 0, stream>>>(vg, u);
    k_main<<<dim3(1024), dim3(256), 0, stream>>>(
        vg, u, xs, T, Wq, bq, Wk, bk, outq, outk);
}